// Round 2
// baseline (939.596 us; speedup 1.0000x reference)
//
#include <hip/hip_runtime.h>
#include <hip/hip_bf16.h>
#include <cstdint>

#define N_NODES 50000
#define N_EDGES 800000

__device__ __forceinline__ float lrelu(float x) { return x >= 0.f ? x : 0.2f * x; }

__device__ __forceinline__ float wsum(float v) {
#pragma unroll
  for (int o = 32; o; o >>= 1) v += __shfl_xor(v, o);
  return v;
}

// select v[h] without runtime register indexing (avoids scratch spill)
__device__ __forceinline__ float sel4(float v0, float v1, float v2, float v3, int h) {
  float r = v0;
  r = (h == 1) ? v1 : r;
  r = (h == 2) ? v2 : r;
  r = (h == 3) ? v3 : r;
  return r;
}

// ---------------- CSR build ----------------

__global__ __launch_bounds__(256) void k_hist(const int* __restrict__ ei, int* __restrict__ cnt, int E) {
  int e = blockIdx.x * 256 + threadIdx.x;
  if (e < E) atomicAdd(&cnt[ei[E + e]], 1);
}

__global__ __launch_bounds__(256) void k_scan_partial(const int* __restrict__ cnt, int* __restrict__ partial, int N) {
  int t = threadIdx.x, b = blockIdx.x;
  int sum = 0;
#pragma unroll
  for (int i = 0; i < 4; i++) {
    int idx = b * 1024 + i * 256 + t;
    if (idx < N) sum += cnt[idx];
  }
#pragma unroll
  for (int o = 32; o; o >>= 1) sum += __shfl_xor(sum, o);
  __shared__ int sh[4];
  if ((t & 63) == 0) sh[t >> 6] = sum;
  __syncthreads();
  if (t == 0) partial[b] = sh[0] + sh[1] + sh[2] + sh[3];
}

__global__ __launch_bounds__(64) void k_scan_top(const int* __restrict__ partial, int* __restrict__ pref,
                                                 int nb, int* __restrict__ offN, int total) {
  int l = threadIdx.x;
  int v = (l < nb) ? partial[l] : 0;
  int x = v;
#pragma unroll
  for (int o = 1; o < 64; o <<= 1) {
    int y = __shfl_up(x, o);
    if (l >= o) x += y;
  }
  if (l < nb) pref[l] = x - v;  // exclusive
  if (l == 0) *offN = total;
}

__global__ __launch_bounds__(256) void k_scan_final(const int* __restrict__ cnt, const int* __restrict__ pref,
                                                    int* __restrict__ off, int N) {
  int t = threadIdx.x, b = blockIdx.x;
  int idx0 = b * 1024 + t * 4;
  int v0 = (idx0 + 0 < N) ? cnt[idx0 + 0] : 0;
  int v1 = (idx0 + 1 < N) ? cnt[idx0 + 1] : 0;
  int v2 = (idx0 + 2 < N) ? cnt[idx0 + 2] : 0;
  int v3 = (idx0 + 3 < N) ? cnt[idx0 + 3] : 0;
  int s = v0 + v1 + v2 + v3;
  int lane = t & 63, w = t >> 6;
  int x = s;
#pragma unroll
  for (int o = 1; o < 64; o <<= 1) {
    int y = __shfl_up(x, o);
    if (lane >= o) x += y;
  }
  __shared__ int wtot[4];
  if (lane == 63) wtot[w] = x;
  __syncthreads();
  int woff = 0;
#pragma unroll
  for (int i = 0; i < 4; i++)
    if (i < w) woff += wtot[i];
  int excl = pref[b] + woff + (x - s);
  if (idx0 + 0 < N) off[idx0 + 0] = excl;
  excl += v0;
  if (idx0 + 1 < N) off[idx0 + 1] = excl;
  excl += v1;
  if (idx0 + 2 < N) off[idx0 + 2] = excl;
  excl += v2;
  if (idx0 + 3 < N) off[idx0 + 3] = excl;
}

__global__ __launch_bounds__(256) void k_scatter(const int* __restrict__ ei, const int* __restrict__ off,
                                                 int* __restrict__ cnt, int* __restrict__ srt, int E) {
  int e = blockIdx.x * 256 + threadIdx.x;
  if (e < E) {
    int s = ei[e], d = ei[E + e];
    int p = atomicSub(&cnt[d], 1) - 1;  // reuses histogram, ends at zero (no re-memset)
    srt[off[d] + p] = s;
  }
}

// ---------------- fp32 GEMM: C[N x 2*Mhalf] = A[N x K] @ [B0 | B1] ----------------
// tile 128x64, 256 threads, 8x4 microtile, BK=32, b128 LDS reads in inner loop

__global__ __launch_bounds__(256) void k_gemm(const float* __restrict__ A, const float* __restrict__ B0,
                                              const float* __restrict__ B1, float* __restrict__ C,
                                              int Nrows, int K, int Mhalf) {
  __shared__ float As[32][132];  // row stride 528 B (16B-aligned)
  __shared__ float Bs[32][64];
  int row0 = blockIdx.x * 128;
  int n0g = blockIdx.y * 64;
  const float* B = (n0g < Mhalf) ? B0 : B1;
  int n0 = n0g % Mhalf;
  int t = threadIdx.x;
  int tx = t & 15, ty = t >> 4;
  float acc[8][4];
#pragma unroll
  for (int i = 0; i < 8; i++)
#pragma unroll
    for (int j = 0; j < 4; j++) acc[i][j] = 0.f;
  int M = 2 * Mhalf;
  for (int k0 = 0; k0 < K; k0 += 32) {
#pragma unroll
    for (int i = 0; i < 4; i++) {
      int idx = t + i * 256;  // 0..1023
      int mrow = idx >> 3;
      int kg = idx & 7;
      int row = row0 + mrow;
      float4 av = make_float4(0.f, 0.f, 0.f, 0.f);
      if (row < Nrows) av = *(const float4*)&A[(size_t)row * K + k0 + kg * 4];
      As[kg * 4 + 0][mrow] = av.x;
      As[kg * 4 + 1][mrow] = av.y;
      As[kg * 4 + 2][mrow] = av.z;
      As[kg * 4 + 3][mrow] = av.w;
    }
#pragma unroll
    for (int i = 0; i < 2; i++) {
      int idx = t + i * 256;  // 0..511
      int kk = idx >> 4;
      int n4 = idx & 15;
      float4 bv = *(const float4*)&B[(size_t)(k0 + kk) * Mhalf + n0 + n4 * 4];
      *(float4*)&Bs[kk][n4 * 4] = bv;
    }
    __syncthreads();
#pragma unroll
    for (int k = 0; k < 32; k++) {
      float4 a0 = *(const float4*)&As[k][ty * 8];
      float4 a1 = *(const float4*)&As[k][ty * 8 + 4];
      float4 b4 = *(const float4*)&Bs[k][tx * 4];
      float a[8] = {a0.x, a0.y, a0.z, a0.w, a1.x, a1.y, a1.z, a1.w};
      float bb[4] = {b4.x, b4.y, b4.z, b4.w};
#pragma unroll
      for (int i = 0; i < 8; i++)
#pragma unroll
        for (int j = 0; j < 4; j++) acc[i][j] = fmaf(a[i], bb[j], acc[i][j]);
    }
    __syncthreads();
  }
#pragma unroll
  for (int i = 0; i < 8; i++) {
    int row = row0 + ty * 8 + i;
    if (row < Nrows) *(float4*)&C[(size_t)row * M + n0g + tx * 4] = *(float4*)&acc[i][0];
  }
}

// ---------------- attention scalar dots ----------------

__global__ __launch_bounds__(256) void k_att0(const float* __restrict__ h0, const float* __restrict__ wsp,
                                              const float* __restrict__ wdp, const float* __restrict__ wsn,
                                              const float* __restrict__ wdn, float* __restrict__ osp,
                                              float* __restrict__ odp, float* __restrict__ osn,
                                              float* __restrict__ odn, int N) {
  int n = blockIdx.x * 4 + (threadIdx.x >> 6);
  if (n >= N) return;
  int l = threadIdx.x & 63;
  const float* row = h0 + (size_t)n * 512;
#pragma unroll
  for (int j = 0; j < 4; j++) {
    float v = row[j * 64 + l];
    float rs = wsum(v * wsp[j * 64 + l]);
    float rd = wsum(v * wdp[j * 64 + l]);
    if (l == 0) {
      osp[n * 4 + j] = rs;
      odp[n * 4 + j] = rd;
    }
  }
#pragma unroll
  for (int j = 0; j < 4; j++) {
    float v = row[256 + j * 64 + l];
    float rs = wsum(v * wsn[j * 64 + l]);
    float rd = wsum(v * wdn[j * 64 + l]);
    if (l == 0) {
      osn[n * 4 + j] = rs;
      odn[n * 4 + j] = rd;
    }
  }
}

__global__ __launch_bounds__(256) void k_att1(const float* __restrict__ h1, const float* __restrict__ wsp,
                                              const float* __restrict__ wdp, const float* __restrict__ wsn,
                                              const float* __restrict__ wdn, float* __restrict__ osp,
                                              float* __restrict__ odp, float* __restrict__ osn,
                                              float* __restrict__ odn, int N) {
  int n = blockIdx.x * 4 + (threadIdx.x >> 6);
  if (n >= N) return;
  int l = threadIdx.x & 63;
  const float* row = h1 + (size_t)n * 128;
  float v0 = row[l], v1 = row[64 + l];
  float a = wsum(v0 * wsp[l]);
  float b = wsum(v0 * wdp[l]);
  float c = wsum(v1 * wsn[l]);
  float d = wsum(v1 * wdn[l]);
  if (l == 0) {
    osp[n] = a;
    odp[n] = b;
    osn[n] = c;
    odn[n] = d;
  }
}

// ---------------- layer-0 aggregation: wave per node, 4 heads x 64 ch ----------------
// mode 0: xbuf = acc + bias        (pos)
// mode 1: xbuf = elu(prev - acc - bias)   (neg, fused with elu)

__global__ __launch_bounds__(256) void k_agg0(const float* __restrict__ h0, int colOff,
                                              const float* __restrict__ as, const float* __restrict__ ad,
                                              const int* __restrict__ off, const int* __restrict__ srt,
                                              const float* __restrict__ bias, float* __restrict__ xbuf,
                                              int mode, int N) {
  int n = blockIdx.x * 4 + (threadIdx.x >> 6);
  if (n >= N) return;
  int l = threadIdx.x & 63;
  int hl = l >> 4;
  int base = off[n];
  int deg = off[n + 1] - base;
  float4 adv4 = *(const float4*)&ad[(size_t)n * 4];
  float4 asn4 = *(const float4*)&as[(size_t)n * 4];
  float m0 = -1e30f, m1 = -1e30f, m2 = -1e30f, m3 = -1e30f;
  float s0 = 0.f, s1 = 0.f, s2 = 0.f, s3 = 0.f;
  if (l == 0) {  // self edge seeds lane 0
    m0 = lrelu(asn4.x + adv4.x); s0 = 1.f;
    m1 = lrelu(asn4.y + adv4.y); s1 = 1.f;
    m2 = lrelu(asn4.z + adv4.z); s2 = 1.f;
    m3 = lrelu(asn4.w + adv4.w); s3 = 1.f;
  }
  for (int i = l; i < deg; i += 64) {
    int sidx = srt[base + i];
    float4 av = *(const float4*)&as[(size_t)sidx * 4];
    {
      float e = lrelu(av.x + adv4.x);
      float nm = fmaxf(m0, e);
      s0 = s0 * __expf(m0 - nm) + __expf(e - nm);
      m0 = nm;
    }
    {
      float e = lrelu(av.y + adv4.y);
      float nm = fmaxf(m1, e);
      s1 = s1 * __expf(m1 - nm) + __expf(e - nm);
      m1 = nm;
    }
    {
      float e = lrelu(av.z + adv4.z);
      float nm = fmaxf(m2, e);
      s2 = s2 * __expf(m2 - nm) + __expf(e - nm);
      m2 = nm;
    }
    {
      float e = lrelu(av.w + adv4.w);
      float nm = fmaxf(m3, e);
      s3 = s3 * __expf(m3 - nm) + __expf(e - nm);
      m3 = nm;
    }
  }
#pragma unroll
  for (int o = 32; o; o >>= 1) {
    float mo, so, nm;
    mo = __shfl_xor(m0, o); so = __shfl_xor(s0, o);
    nm = fmaxf(m0, mo); s0 = s0 * __expf(m0 - nm) + so * __expf(mo - nm); m0 = nm;
    mo = __shfl_xor(m1, o); so = __shfl_xor(s1, o);
    nm = fmaxf(m1, mo); s1 = s1 * __expf(m1 - nm) + so * __expf(mo - nm); m1 = nm;
    mo = __shfl_xor(m2, o); so = __shfl_xor(s2, o);
    nm = fmaxf(m2, mo); s2 = s2 * __expf(m2 - nm) + so * __expf(mo - nm); m2 = nm;
    mo = __shfl_xor(m3, o); so = __shfl_xor(s3, o);
    nm = fmaxf(m3, mo); s3 = s3 * __expf(m3 - nm) + so * __expf(mo - nm); m3 = nm;
  }
  float mh = sel4(m0, m1, m2, m3, hl);
  float inv = 1.f / (sel4(s0, s1, s2, s3, hl) + 1e-16f);
  float adh = sel4(adv4.x, adv4.y, adv4.z, adv4.w, hl);
  float ash = sel4(asn4.x, asn4.y, asn4.z, asn4.w, hl);
  float accx, accy, accz, accw;
  {
    float w = __expf(lrelu(ash + adh) - mh) * inv;
    float4 hv = *(const float4*)&h0[(size_t)n * 512 + colOff + l * 4];
    accx = w * hv.x; accy = w * hv.y; accz = w * hv.z; accw = w * hv.w;
  }
  for (int j = 0; j < deg; j++) {
    int sidx = srt[base + j];
    float w = __expf(lrelu(as[(size_t)sidx * 4 + hl] + adh) - mh) * inv;
    float4 hv = *(const float4*)&h0[(size_t)sidx * 512 + colOff + l * 4];
    accx = fmaf(w, hv.x, accx);
    accy = fmaf(w, hv.y, accy);
    accz = fmaf(w, hv.z, accz);
    accw = fmaf(w, hv.w, accw);
  }
  float4 bv = *(const float4*)&bias[l * 4];
  float* outp = &xbuf[(size_t)n * 256 + l * 4];
  if (mode == 0) {
    float4 r;
    r.x = accx + bv.x; r.y = accy + bv.y; r.z = accz + bv.z; r.w = accw + bv.w;
    *(float4*)outp = r;
  } else {
    float4 prev = *(const float4*)outp;
    float rx = prev.x - accx - bv.x;
    float ry = prev.y - accy - bv.y;
    float rz = prev.z - accz - bv.z;
    float rw = prev.w - accw - bv.w;
    float4 r;
    r.x = rx > 0.f ? rx : expm1f(rx);
    r.y = ry > 0.f ? ry : expm1f(ry);
    r.z = rz > 0.f ? rz : expm1f(rz);
    r.w = rw > 0.f ? rw : expm1f(rw);
    *(float4*)outp = r;
  }
}

// ---------------- layer-1 aggregation: wave per node, 1 head x 64 ch ----------------
// mode 0: out = acc + bias   (pos);  mode 1: out -= acc + bias   (neg)

__global__ __launch_bounds__(256) void k_agg1(const float* __restrict__ h1, int colOff,
                                              const float* __restrict__ as, const float* __restrict__ ad,
                                              const int* __restrict__ off, const int* __restrict__ srt,
                                              const float* __restrict__ bias, float* __restrict__ out,
                                              int mode, int N) {
  int n = blockIdx.x * 4 + (threadIdx.x >> 6);
  if (n >= N) return;
  int l = threadIdx.x & 63;
  int base = off[n];
  int deg = off[n + 1] - base;
  float adn = ad[n], asnv = as[n];
  float m = -1e30f, sden = 0.f;
  if (l == 0) {
    m = lrelu(asnv + adn);
    sden = 1.f;
  }
  for (int i = l; i < deg; i += 64) {
    float e = lrelu(as[srt[base + i]] + adn);
    float nm = fmaxf(m, e);
    sden = sden * __expf(m - nm) + __expf(e - nm);
    m = nm;
  }
#pragma unroll
  for (int o = 32; o; o >>= 1) {
    float mo = __shfl_xor(m, o);
    float so = __shfl_xor(sden, o);
    float nm = fmaxf(m, mo);
    sden = sden * __expf(m - nm) + so * __expf(mo - nm);
    m = nm;
  }
  float inv = 1.f / (sden + 1e-16f);
  float acc;
  {
    float w = __expf(lrelu(asnv + adn) - m) * inv;
    acc = w * h1[(size_t)n * 128 + colOff + l];
  }
  for (int j = 0; j < deg; j++) {
    int sidx = srt[base + j];
    float w = __expf(lrelu(as[sidx] + adn) - m) * inv;
    acc = fmaf(w, h1[(size_t)sidx * 128 + colOff + l], acc);
  }
  float r = acc + bias[l];
  float* op = &out[(size_t)n * 64 + l];
  if (mode == 0)
    *op = r;
  else
    *op = *op - r;
}

// ---------------- launch ----------------

extern "C" void kernel_launch(void* const* d_in, const int* in_sizes, int n_in,
                              void* d_out, int out_size, void* d_ws, size_t ws_size,
                              hipStream_t stream) {
  const float* x = (const float*)d_in[0];
  const int* ep = (const int*)d_in[1];
  const int* en = (const int*)d_in[2];
  const float* W0p = (const float*)d_in[3];
  const float* asrc0p = (const float*)d_in[4];
  const float* adst0p = (const float*)d_in[5];
  const float* b0p = (const float*)d_in[6];
  const float* W0n = (const float*)d_in[7];
  const float* asrc0n = (const float*)d_in[8];
  const float* adst0n = (const float*)d_in[9];
  const float* b0n = (const float*)d_in[10];
  const float* W1p = (const float*)d_in[11];
  const float* asrc1p = (const float*)d_in[12];
  const float* adst1p = (const float*)d_in[13];
  const float* b1p = (const float*)d_in[14];
  const float* W1n = (const float*)d_in[15];
  const float* asrc1n = (const float*)d_in[16];
  const float* adst1n = (const float*)d_in[17];
  const float* b1n = (const float*)d_in[18];

  const int N = N_NODES, E = N_EDGES;
  char* base = (char*)d_ws;
  size_t o = 0;
  auto alloc = [&](size_t bytes) -> void* {
    void* r = base + o;
    o = (o + bytes + 255) & ~(size_t)255;
    return r;
  };
  int* cnt_p = (int*)alloc((size_t)N * 4);
  int* cnt_n = (int*)alloc((size_t)N * 4);
  size_t cntBytes = o;  // memset covers both count arrays (+padding)
  int* off_p = (int*)alloc((size_t)(N + 1) * 4);
  int* off_n = (int*)alloc((size_t)(N + 1) * 4);
  int* part_p = (int*)alloc(1024 * 4);
  int* part_n = (int*)alloc(1024 * 4);
  int* pref_p = (int*)alloc(1024 * 4);
  int* pref_n = (int*)alloc(1024 * 4);
  int* srt_p = (int*)alloc((size_t)E * 4);
  int* srt_n = (int*)alloc((size_t)E * 4);
  float* h0 = (float*)alloc((size_t)N * 512 * 4);
  float* as0p = (float*)alloc((size_t)N * 4 * 4);
  float* ad0p = (float*)alloc((size_t)N * 4 * 4);
  float* as0n = (float*)alloc((size_t)N * 4 * 4);
  float* ad0n = (float*)alloc((size_t)N * 4 * 4);
  float* as1p = (float*)alloc((size_t)N * 4);
  float* ad1p = (float*)alloc((size_t)N * 4);
  float* as1n = (float*)alloc((size_t)N * 4);
  float* ad1n = (float*)alloc((size_t)N * 4);
  float* xbuf = (float*)alloc((size_t)N * 256 * 4);
  float* h1 = h0;  // alias: h0 dead once layer-0 aggregation completes

  hipMemsetAsync(base, 0, cntBytes, stream);

  int egrid = (E + 255) / 256;
  k_hist<<<egrid, 256, 0, stream>>>(ep, cnt_p, E);
  k_hist<<<egrid, 256, 0, stream>>>(en, cnt_n, E);
  int nb = (N + 1023) / 1024;  // 49
  k_scan_partial<<<nb, 256, 0, stream>>>(cnt_p, part_p, N);
  k_scan_partial<<<nb, 256, 0, stream>>>(cnt_n, part_n, N);
  k_scan_top<<<1, 64, 0, stream>>>(part_p, pref_p, nb, off_p + N, E);
  k_scan_top<<<1, 64, 0, stream>>>(part_n, pref_n, nb, off_n + N, E);
  k_scan_final<<<nb, 256, 0, stream>>>(cnt_p, pref_p, off_p, N);
  k_scan_final<<<nb, 256, 0, stream>>>(cnt_n, pref_n, off_n, N);
  k_scatter<<<egrid, 256, 0, stream>>>(ep, off_p, cnt_p, srt_p, E);
  k_scatter<<<egrid, 256, 0, stream>>>(en, off_n, cnt_n, srt_n, E);

  // layer 0
  dim3 g0((N + 127) / 128, 8);
  k_gemm<<<g0, 256, 0, stream>>>(x, W0p, W0n, h0, N, 128, 256);
  int ngrid = (N + 3) / 4;
  k_att0<<<ngrid, 256, 0, stream>>>(h0, asrc0p, adst0p, asrc0n, adst0n, as0p, ad0p, as0n, ad0n, N);
  k_agg0<<<ngrid, 256, 0, stream>>>(h0, 0, as0p, ad0p, off_p, srt_p, b0p, xbuf, 0, N);
  k_agg0<<<ngrid, 256, 0, stream>>>(h0, 256, as0n, ad0n, off_n, srt_n, b0n, xbuf, 1, N);

  // layer 1
  dim3 g1((N + 127) / 128, 2);
  k_gemm<<<g1, 256, 0, stream>>>(xbuf, W1p, W1n, h1, N, 256, 64);
  k_att1<<<ngrid, 256, 0, stream>>>(h1, asrc1p, adst1p, asrc1n, adst1n, as1p, ad1p, as1n, ad1n, N);
  float* outF = (float*)d_out;
  k_agg1<<<ngrid, 256, 0, stream>>>(h1, 0, as1p, ad1p, off_p, srt_p, b1p, outF, 0, N);
  k_agg1<<<ngrid, 256, 0, stream>>>(h1, 64, as1n, ad1n, off_n, srt_n, b1n, outF, 1, N);
}

// Round 3
// 787.611 us; speedup vs baseline: 1.1930x; 1.1930x over previous
//
#include <hip/hip_runtime.h>
#include <cstdint>

#define N_NODES 50000
#define N_EDGES 800000

__device__ __forceinline__ float lrelu(float x) { return x >= 0.f ? x : 0.2f * x; }

__device__ __forceinline__ void onup(float& m, float& s, float e) {
  float nm = fmaxf(m, e);
  s = s * __expf(m - nm) + __expf(e - nm);
  m = nm;
}

// select v[h] without runtime register indexing (avoids scratch spill)
__device__ __forceinline__ float sel4(float v0, float v1, float v2, float v3, int h) {
  float r = v0;
  r = (h == 1) ? v1 : r;
  r = (h == 2) ? v2 : r;
  r = (h == 3) ? v3 : r;
  return r;
}

// ---------------- CSR build ----------------

__global__ __launch_bounds__(256) void k_hist(const int* __restrict__ ei, int* __restrict__ cnt, int E) {
  int e = blockIdx.x * 256 + threadIdx.x;
  if (e < E) atomicAdd(&cnt[ei[E + e]], 1);
}

__global__ __launch_bounds__(256) void k_scan_partial(const int* __restrict__ cnt, int* __restrict__ partial, int N) {
  int t = threadIdx.x, b = blockIdx.x;
  int sum = 0;
#pragma unroll
  for (int i = 0; i < 4; i++) {
    int idx = b * 1024 + i * 256 + t;
    if (idx < N) sum += cnt[idx];
  }
#pragma unroll
  for (int o = 32; o; o >>= 1) sum += __shfl_xor(sum, o);
  __shared__ int sh[4];
  if ((t & 63) == 0) sh[t >> 6] = sum;
  __syncthreads();
  if (t == 0) partial[b] = sh[0] + sh[1] + sh[2] + sh[3];
}

__global__ __launch_bounds__(64) void k_scan_top(const int* __restrict__ partial, int* __restrict__ pref,
                                                 int nb, int* __restrict__ offN, int total) {
  int l = threadIdx.x;
  int v = (l < nb) ? partial[l] : 0;
  int x = v;
#pragma unroll
  for (int o = 1; o < 64; o <<= 1) {
    int y = __shfl_up(x, o);
    if (l >= o) x += y;
  }
  if (l < nb) pref[l] = x - v;  // exclusive
  if (l == 0) *offN = total;
}

__global__ __launch_bounds__(256) void k_scan_final(const int* __restrict__ cnt, const int* __restrict__ pref,
                                                    int* __restrict__ off, int N) {
  int t = threadIdx.x, b = blockIdx.x;
  int idx0 = b * 1024 + t * 4;
  int v0 = (idx0 + 0 < N) ? cnt[idx0 + 0] : 0;
  int v1 = (idx0 + 1 < N) ? cnt[idx0 + 1] : 0;
  int v2 = (idx0 + 2 < N) ? cnt[idx0 + 2] : 0;
  int v3 = (idx0 + 3 < N) ? cnt[idx0 + 3] : 0;
  int s = v0 + v1 + v2 + v3;
  int lane = t & 63, w = t >> 6;
  int x = s;
#pragma unroll
  for (int o = 1; o < 64; o <<= 1) {
    int y = __shfl_up(x, o);
    if (lane >= o) x += y;
  }
  __shared__ int wtot[4];
  if (lane == 63) wtot[w] = x;
  __syncthreads();
  int woff = 0;
#pragma unroll
  for (int i = 0; i < 4; i++)
    if (i < w) woff += wtot[i];
  int excl = pref[b] + woff + (x - s);
  if (idx0 + 0 < N) off[idx0 + 0] = excl;
  excl += v0;
  if (idx0 + 1 < N) off[idx0 + 1] = excl;
  excl += v1;
  if (idx0 + 2 < N) off[idx0 + 2] = excl;
  excl += v2;
  if (idx0 + 3 < N) off[idx0 + 3] = excl;
}

__global__ __launch_bounds__(256) void k_scatter(const int* __restrict__ ei, const int* __restrict__ off,
                                                 int* __restrict__ cnt, int* __restrict__ srt, int E) {
  int e = blockIdx.x * 256 + threadIdx.x;
  if (e < E) {
    int s = ei[e], d = ei[E + e];
    int p = atomicSub(&cnt[d], 1) - 1;  // reuses histogram, ends at zero (no re-memset)
    srt[off[d] + p] = s;
  }
}

// ---------------- fp32 GEMM: C[N x 2*Mhalf] = A[N x K] @ [B0 | B1] ----------------
// tile 128x64, 256 threads, 8x4 microtile, BK=32, b128 LDS reads.
// Epilogue: attention dots. Each blockIdx.y covers exactly one 64-ch head
// (pos half if n0g<Mhalf else neg). 16-lane shfl reduce over the col dim.

__global__ __launch_bounds__(256) void k_gemm(const float* __restrict__ A, const float* __restrict__ B0,
                                              const float* __restrict__ B1, float* __restrict__ C,
                                              int Nrows, int K, int Mhalf,
                                              const float* __restrict__ attSP, const float* __restrict__ attDP,
                                              const float* __restrict__ attSN, const float* __restrict__ attDN,
                                              float* __restrict__ oSP, float* __restrict__ oDP,
                                              float* __restrict__ oSN, float* __restrict__ oDN) {
  __shared__ float As[32][132];  // row stride 528 B (16B-aligned)
  __shared__ float Bs[32][64];
  int row0 = blockIdx.x * 128;
  int n0g = blockIdx.y * 64;
  const float* B = (n0g < Mhalf) ? B0 : B1;
  int n0 = n0g % Mhalf;
  int t = threadIdx.x;
  int tx = t & 15, ty = t >> 4;
  float acc[8][4];
#pragma unroll
  for (int i = 0; i < 8; i++)
#pragma unroll
    for (int j = 0; j < 4; j++) acc[i][j] = 0.f;
  int M = 2 * Mhalf;
  for (int k0 = 0; k0 < K; k0 += 32) {
#pragma unroll
    for (int i = 0; i < 4; i++) {
      int idx = t + i * 256;  // 0..1023
      int mrow = idx >> 3;
      int kg = idx & 7;
      int row = row0 + mrow;
      float4 av = make_float4(0.f, 0.f, 0.f, 0.f);
      if (row < Nrows) av = *(const float4*)&A[(size_t)row * K + k0 + kg * 4];
      As[kg * 4 + 0][mrow] = av.x;
      As[kg * 4 + 1][mrow] = av.y;
      As[kg * 4 + 2][mrow] = av.z;
      As[kg * 4 + 3][mrow] = av.w;
    }
#pragma unroll
    for (int i = 0; i < 2; i++) {
      int idx = t + i * 256;  // 0..511
      int kk = idx >> 4;
      int n4 = idx & 15;
      float4 bv = *(const float4*)&B[(size_t)(k0 + kk) * Mhalf + n0 + n4 * 4];
      *(float4*)&Bs[kk][n4 * 4] = bv;
    }
    __syncthreads();
#pragma unroll
    for (int k = 0; k < 32; k++) {
      float4 a0 = *(const float4*)&As[k][ty * 8];
      float4 a1 = *(const float4*)&As[k][ty * 8 + 4];
      float4 b4 = *(const float4*)&Bs[k][tx * 4];
      float a[8] = {a0.x, a0.y, a0.z, a0.w, a1.x, a1.y, a1.z, a1.w};
      float bb[4] = {b4.x, b4.y, b4.z, b4.w};
#pragma unroll
      for (int i = 0; i < 8; i++)
#pragma unroll
        for (int j = 0; j < 4; j++) acc[i][j] = fmaf(a[i], bb[j], acc[i][j]);
    }
    __syncthreads();
  }
#pragma unroll
  for (int i = 0; i < 8; i++) {
    int row = row0 + ty * 8 + i;
    if (row < Nrows) *(float4*)&C[(size_t)row * M + n0g + tx * 4] = *(float4*)&acc[i][0];
  }
  // ---- fused attention dots: a_s[row,head], a_d[row,head] ----
  int isNeg = (n0g >= Mhalf) ? 1 : 0;
  int head = (n0g - (isNeg ? Mhalf : 0)) >> 6;
  int H = Mhalf >> 6;
  const float* wS = (isNeg ? attSN : attSP) + head * 64;
  const float* wD = (isNeg ? attDN : attDP) + head * 64;
  float* oS = isNeg ? oSN : oSP;
  float* oD = isNeg ? oDN : oDP;
  float4 wsv = *(const float4*)&wS[tx * 4];
  float4 wdv = *(const float4*)&wD[tx * 4];
#pragma unroll
  for (int i = 0; i < 8; i++) {
    float ps = acc[i][0] * wsv.x + acc[i][1] * wsv.y + acc[i][2] * wsv.z + acc[i][3] * wsv.w;
    float pd = acc[i][0] * wdv.x + acc[i][1] * wdv.y + acc[i][2] * wdv.z + acc[i][3] * wdv.w;
#pragma unroll
    for (int o = 1; o < 16; o <<= 1) {
      ps += __shfl_xor(ps, o);
      pd += __shfl_xor(pd, o);
    }
    int row = row0 + ty * 8 + i;
    if (tx == 0 && row < Nrows) {
      oS[(size_t)row * H + head] = ps;
      oD[(size_t)row * H + head] = pd;
    }
  }
}

// ---------------- softmax stats helper (4 heads / wave-per-node) ----------------

struct MS4 { float m0, m1, m2, m3, s0, s1, s2, s3; };

__device__ __forceinline__ MS4 stats_heads(const float* __restrict__ as, float4 sl, float4 ad,
                                           const int* __restrict__ srt, int base, int deg, int l) {
  MS4 r;
  r.m0 = r.m1 = r.m2 = r.m3 = -1e30f;
  r.s0 = r.s1 = r.s2 = r.s3 = 0.f;
  if (l == 0) {  // self edge seeds lane 0
    r.m0 = lrelu(sl.x + ad.x); r.s0 = 1.f;
    r.m1 = lrelu(sl.y + ad.y); r.s1 = 1.f;
    r.m2 = lrelu(sl.z + ad.z); r.s2 = 1.f;
    r.m3 = lrelu(sl.w + ad.w); r.s3 = 1.f;
  }
  for (int i = l; i < deg; i += 64) {
    int s = srt[base + i];
    float4 av = *(const float4*)&as[(size_t)s * 4];
    onup(r.m0, r.s0, lrelu(av.x + ad.x));
    onup(r.m1, r.s1, lrelu(av.y + ad.y));
    onup(r.m2, r.s2, lrelu(av.z + ad.z));
    onup(r.m3, r.s3, lrelu(av.w + ad.w));
  }
#pragma unroll
  for (int o = 32; o; o >>= 1) {
    float mo, so, nm;
    mo = __shfl_xor(r.m0, o); so = __shfl_xor(r.s0, o);
    nm = fmaxf(r.m0, mo); r.s0 = r.s0 * __expf(r.m0 - nm) + so * __expf(mo - nm); r.m0 = nm;
    mo = __shfl_xor(r.m1, o); so = __shfl_xor(r.s1, o);
    nm = fmaxf(r.m1, mo); r.s1 = r.s1 * __expf(r.m1 - nm) + so * __expf(mo - nm); r.m1 = nm;
    mo = __shfl_xor(r.m2, o); so = __shfl_xor(r.s2, o);
    nm = fmaxf(r.m2, mo); r.s2 = r.s2 * __expf(r.m2 - nm) + so * __expf(mo - nm); r.m2 = nm;
    mo = __shfl_xor(r.m3, o); so = __shfl_xor(r.s3, o);
    nm = fmaxf(r.m3, mo); r.s3 = r.s3 * __expf(r.m3 - nm) + so * __expf(mo - nm); r.m3 = nm;
  }
  return r;
}

// weighted gather, 4-way unrolled for memory-level parallelism
__device__ __forceinline__ float4 gather_head(const float* __restrict__ h0, int colIdx,
                                              const float* __restrict__ as, int hl, float adh,
                                              float mh, float inv, float wself, int n,
                                              const int* __restrict__ srt, int base, int deg) {
  float4 acc;
  {
    float4 hv = *(const float4*)&h0[(size_t)n * 512 + colIdx];
    acc.x = wself * hv.x; acc.y = wself * hv.y; acc.z = wself * hv.z; acc.w = wself * hv.w;
  }
  int j = 0;
  for (; j + 4 <= deg; j += 4) {
    int sa = srt[base + j + 0], sb = srt[base + j + 1];
    int sc = srt[base + j + 2], sd = srt[base + j + 3];
    float4 ha = *(const float4*)&h0[(size_t)sa * 512 + colIdx];
    float4 hb = *(const float4*)&h0[(size_t)sb * 512 + colIdx];
    float4 hc = *(const float4*)&h0[(size_t)sc * 512 + colIdx];
    float4 hd = *(const float4*)&h0[(size_t)sd * 512 + colIdx];
    float wa = __expf(lrelu(as[(size_t)sa * 4 + hl] + adh) - mh) * inv;
    float wb = __expf(lrelu(as[(size_t)sb * 4 + hl] + adh) - mh) * inv;
    float wc = __expf(lrelu(as[(size_t)sc * 4 + hl] + adh) - mh) * inv;
    float wd = __expf(lrelu(as[(size_t)sd * 4 + hl] + adh) - mh) * inv;
    acc.x = fmaf(wa, ha.x, fmaf(wb, hb.x, fmaf(wc, hc.x, fmaf(wd, hd.x, acc.x))));
    acc.y = fmaf(wa, ha.y, fmaf(wb, hb.y, fmaf(wc, hc.y, fmaf(wd, hd.y, acc.y))));
    acc.z = fmaf(wa, ha.z, fmaf(wb, hb.z, fmaf(wc, hc.z, fmaf(wd, hd.z, acc.z))));
    acc.w = fmaf(wa, ha.w, fmaf(wb, hb.w, fmaf(wc, hc.w, fmaf(wd, hd.w, acc.w))));
  }
  for (; j < deg; j++) {
    int s = srt[base + j];
    float4 hv = *(const float4*)&h0[(size_t)s * 512 + colIdx];
    float w = __expf(lrelu(as[(size_t)s * 4 + hl] + adh) - mh) * inv;
    acc.x = fmaf(w, hv.x, acc.x);
    acc.y = fmaf(w, hv.y, acc.y);
    acc.z = fmaf(w, hv.z, acc.z);
    acc.w = fmaf(w, hv.w, acc.w);
  }
  return acc;
}

// ---------------- fused layer-0 aggregation (pos + neg + bias + elu) ----------------
// wave per node; 64 lanes x float4 = 256 channels per half.

__global__ __launch_bounds__(256) void k_agg0f(const float* __restrict__ h0,
                                               const float* __restrict__ asP, const float* __restrict__ adP,
                                               const float* __restrict__ asN, const float* __restrict__ adN,
                                               const int* __restrict__ offP, const int* __restrict__ srtP,
                                               const int* __restrict__ offN, const int* __restrict__ srtN,
                                               const float* __restrict__ bP, const float* __restrict__ bN,
                                               float* __restrict__ xbuf, int N) {
  int n = blockIdx.x * 4 + (threadIdx.x >> 6);
  if (n >= N) return;
  int l = threadIdx.x & 63;
  int hl = l >> 4;

  // ---- positive half (cols 0..255) ----
  int baseP = offP[n];
  int degP = offP[n + 1] - baseP;
  float4 adp4 = *(const float4*)&adP[(size_t)n * 4];
  float4 asp4 = *(const float4*)&asP[(size_t)n * 4];
  MS4 P = stats_heads(asP, asp4, adp4, srtP, baseP, degP, l);
  float mhP = sel4(P.m0, P.m1, P.m2, P.m3, hl);
  float invP = 1.f / (sel4(P.s0, P.s1, P.s2, P.s3, hl) + 1e-16f);
  float adhP = sel4(adp4.x, adp4.y, adp4.z, adp4.w, hl);
  float ashP = sel4(asp4.x, asp4.y, asp4.z, asp4.w, hl);
  float wselfP = __expf(lrelu(ashP + adhP) - mhP) * invP;
  float4 accP = gather_head(h0, l * 4, asP, hl, adhP, mhP, invP, wselfP, n, srtP, baseP, degP);

  // ---- negative half (cols 256..511) ----
  int baseN = offN[n];
  int degN = offN[n + 1] - baseN;
  float4 adn4 = *(const float4*)&adN[(size_t)n * 4];
  float4 asn4 = *(const float4*)&asN[(size_t)n * 4];
  MS4 Q = stats_heads(asN, asn4, adn4, srtN, baseN, degN, l);
  float mhN = sel4(Q.m0, Q.m1, Q.m2, Q.m3, hl);
  float invN = 1.f / (sel4(Q.s0, Q.s1, Q.s2, Q.s3, hl) + 1e-16f);
  float adhN = sel4(adn4.x, adn4.y, adn4.z, adn4.w, hl);
  float ashN = sel4(asn4.x, asn4.y, asn4.z, asn4.w, hl);
  float wselfN = __expf(lrelu(ashN + adhN) - mhN) * invN;
  float4 accN = gather_head(h0, 256 + l * 4, asN, hl, adhN, mhN, invN, wselfN, n, srtN, baseN, degN);

  // ---- combine: elu((accP+bP) - (accN+bN)) ----
  float4 bp = *(const float4*)&bP[l * 4];
  float4 bn = *(const float4*)&bN[l * 4];
  float rx = accP.x + bp.x - accN.x - bn.x;
  float ry = accP.y + bp.y - accN.y - bn.y;
  float rz = accP.z + bp.z - accN.z - bn.z;
  float rw = accP.w + bp.w - accN.w - bn.w;
  float4 r;
  r.x = rx > 0.f ? rx : expm1f(rx);
  r.y = ry > 0.f ? ry : expm1f(ry);
  r.z = rz > 0.f ? rz : expm1f(rz);
  r.w = rw > 0.f ? rw : expm1f(rw);
  *(float4*)&xbuf[(size_t)n * 256 + l * 4] = r;
}

// ---------------- fused layer-1 aggregation (pos - neg), 64 ch ----------------

__device__ __forceinline__ void stats1(const float* __restrict__ as, float sl, float ad,
                                       const int* __restrict__ srt, int base, int deg, int l,
                                       float& m, float& s) {
  m = -1e30f;
  s = 0.f;
  if (l == 0) {
    m = lrelu(sl + ad);
    s = 1.f;
  }
  for (int i = l; i < deg; i += 64) onup(m, s, lrelu(as[srt[base + i]] + ad));
#pragma unroll
  for (int o = 32; o; o >>= 1) {
    float mo = __shfl_xor(m, o);
    float so = __shfl_xor(s, o);
    float nm = fmaxf(m, mo);
    s = s * __expf(m - nm) + so * __expf(mo - nm);
    m = nm;
  }
}

__device__ __forceinline__ float gather1(const float* __restrict__ h1, int colIdx,
                                         const float* __restrict__ as, float ad, float mh, float inv,
                                         float wself, int n, const int* __restrict__ srt, int base, int deg) {
  float acc = wself * h1[(size_t)n * 128 + colIdx];
  int j = 0;
  for (; j + 4 <= deg; j += 4) {
    int sa = srt[base + j + 0], sb = srt[base + j + 1];
    int sc = srt[base + j + 2], sd = srt[base + j + 3];
    float ha = h1[(size_t)sa * 128 + colIdx];
    float hb = h1[(size_t)sb * 128 + colIdx];
    float hc = h1[(size_t)sc * 128 + colIdx];
    float hd = h1[(size_t)sd * 128 + colIdx];
    float wa = __expf(lrelu(as[sa] + ad) - mh) * inv;
    float wb = __expf(lrelu(as[sb] + ad) - mh) * inv;
    float wc = __expf(lrelu(as[sc] + ad) - mh) * inv;
    float wd = __expf(lrelu(as[sd] + ad) - mh) * inv;
    acc = fmaf(wa, ha, fmaf(wb, hb, fmaf(wc, hc, fmaf(wd, hd, acc))));
  }
  for (; j < deg; j++) {
    int s = srt[base + j];
    float w = __expf(lrelu(as[s] + ad) - mh) * inv;
    acc = fmaf(w, h1[(size_t)s * 128 + colIdx], acc);
  }
  return acc;
}

__global__ __launch_bounds__(256) void k_agg1f(const float* __restrict__ h1,
                                               const float* __restrict__ asP, const float* __restrict__ adP,
                                               const float* __restrict__ asN, const float* __restrict__ adN,
                                               const int* __restrict__ offP, const int* __restrict__ srtP,
                                               const int* __restrict__ offN, const int* __restrict__ srtN,
                                               const float* __restrict__ bP, const float* __restrict__ bN,
                                               float* __restrict__ out, int N) {
  int n = blockIdx.x * 4 + (threadIdx.x >> 6);
  if (n >= N) return;
  int l = threadIdx.x & 63;

  int baseP = offP[n];
  int degP = offP[n + 1] - baseP;
  float adp = adP[n], asp = asP[n];
  float mP, sP;
  stats1(asP, asp, adp, srtP, baseP, degP, l, mP, sP);
  float invP = 1.f / (sP + 1e-16f);
  float wselfP = __expf(lrelu(asp + adp) - mP) * invP;
  float accP = gather1(h1, l, asP, adp, mP, invP, wselfP, n, srtP, baseP, degP);

  int baseN = offN[n];
  int degN = offN[n + 1] - baseN;
  float adn = adN[n], asn = asN[n];
  float mN, sN;
  stats1(asN, asn, adn, srtN, baseN, degN, l, mN, sN);
  float invN = 1.f / (sN + 1e-16f);
  float wselfN = __expf(lrelu(asn + adn) - mN) * invN;
  float accN = gather1(h1, 64 + l, asN, adn, mN, invN, wselfN, n, srtN, baseN, degN);

  out[(size_t)n * 64 + l] = (accP + bP[l]) - (accN + bN[l]);
}

// ---------------- launch ----------------

extern "C" void kernel_launch(void* const* d_in, const int* in_sizes, int n_in,
                              void* d_out, int out_size, void* d_ws, size_t ws_size,
                              hipStream_t stream) {
  const float* x = (const float*)d_in[0];
  const int* ep = (const int*)d_in[1];
  const int* en = (const int*)d_in[2];
  const float* W0p = (const float*)d_in[3];
  const float* asrc0p = (const float*)d_in[4];
  const float* adst0p = (const float*)d_in[5];
  const float* b0p = (const float*)d_in[6];
  const float* W0n = (const float*)d_in[7];
  const float* asrc0n = (const float*)d_in[8];
  const float* adst0n = (const float*)d_in[9];
  const float* b0n = (const float*)d_in[10];
  const float* W1p = (const float*)d_in[11];
  const float* asrc1p = (const float*)d_in[12];
  const float* adst1p = (const float*)d_in[13];
  const float* b1p = (const float*)d_in[14];
  const float* W1n = (const float*)d_in[15];
  const float* asrc1n = (const float*)d_in[16];
  const float* adst1n = (const float*)d_in[17];
  const float* b1n = (const float*)d_in[18];

  const int N = N_NODES, E = N_EDGES;
  char* base = (char*)d_ws;
  size_t o = 0;
  auto alloc = [&](size_t bytes) -> void* {
    void* r = base + o;
    o = (o + bytes + 255) & ~(size_t)255;
    return r;
  };
  int* cnt_p = (int*)alloc((size_t)N * 4);
  int* cnt_n = (int*)alloc((size_t)N * 4);
  size_t cntBytes = o;  // memset covers both count arrays (+padding)
  int* off_p = (int*)alloc((size_t)(N + 1) * 4);
  int* off_n = (int*)alloc((size_t)(N + 1) * 4);
  int* part_p = (int*)alloc(1024 * 4);
  int* part_n = (int*)alloc(1024 * 4);
  int* pref_p = (int*)alloc(1024 * 4);
  int* pref_n = (int*)alloc(1024 * 4);
  int* srt_p = (int*)alloc((size_t)E * 4);
  int* srt_n = (int*)alloc((size_t)E * 4);
  float* h0 = (float*)alloc((size_t)N * 512 * 4);
  float* as0p = (float*)alloc((size_t)N * 4 * 4);
  float* ad0p = (float*)alloc((size_t)N * 4 * 4);
  float* as0n = (float*)alloc((size_t)N * 4 * 4);
  float* ad0n = (float*)alloc((size_t)N * 4 * 4);
  float* as1p = (float*)alloc((size_t)N * 4);
  float* ad1p = (float*)alloc((size_t)N * 4);
  float* as1n = (float*)alloc((size_t)N * 4);
  float* ad1n = (float*)alloc((size_t)N * 4);
  float* xbuf = (float*)alloc((size_t)N * 256 * 4);
  float* h1 = h0;  // alias: h0 dead once layer-0 aggregation completes

  hipMemsetAsync(base, 0, cntBytes, stream);

  int egrid = (E + 255) / 256;
  k_hist<<<egrid, 256, 0, stream>>>(ep, cnt_p, E);
  k_hist<<<egrid, 256, 0, stream>>>(en, cnt_n, E);
  int nb = (N + 1023) / 1024;  // 49
  k_scan_partial<<<nb, 256, 0, stream>>>(cnt_p, part_p, N);
  k_scan_partial<<<nb, 256, 0, stream>>>(cnt_n, part_n, N);
  k_scan_top<<<1, 64, 0, stream>>>(part_p, pref_p, nb, off_p + N, E);
  k_scan_top<<<1, 64, 0, stream>>>(part_n, pref_n, nb, off_n + N, E);
  k_scan_final<<<nb, 256, 0, stream>>>(cnt_p, pref_p, off_p, N);
  k_scan_final<<<nb, 256, 0, stream>>>(cnt_n, pref_n, off_n, N);
  k_scatter<<<egrid, 256, 0, stream>>>(ep, off_p, cnt_p, srt_p, E);
  k_scatter<<<egrid, 256, 0, stream>>>(en, off_n, cnt_n, srt_n, E);

  // layer 0: GEMM (+ fused att dots) then fused aggregation
  dim3 g0((N + 127) / 128, 8);
  k_gemm<<<g0, 256, 0, stream>>>(x, W0p, W0n, h0, N, 128, 256,
                                 asrc0p, adst0p, asrc0n, adst0n,
                                 as0p, ad0p, as0n, ad0n);
  int ngrid = (N + 3) / 4;
  k_agg0f<<<ngrid, 256, 0, stream>>>(h0, as0p, ad0p, as0n, ad0n,
                                     off_p, srt_p, off_n, srt_n, b0p, b0n, xbuf, N);

  // layer 1
  dim3 g1((N + 127) / 128, 2);
  k_gemm<<<g1, 256, 0, stream>>>(xbuf, W1p, W1n, h1, N, 256, 64,
                                 asrc1p, adst1p, asrc1n, adst1n,
                                 as1p, ad1p, as1n, ad1n);
  k_agg1f<<<ngrid, 256, 0, stream>>>(h1, as1p, ad1p, as1n, ad1n,
                                     off_p, srt_p, off_n, srt_n, b1p, b1n, (float*)d_out, N);
}